// Round 1
// baseline (1732.299 us; speedup 1.0000x reference)
//
#include <hip/hip_runtime.h>

#define N_NODES 100000
#define N_EDGES 1600000
#define N_FEAT  16
#define HIDDEN  128
#define N_GRAPHS 512

// ---------------- degree / dinv ----------------

__global__ void k_deg(const int* __restrict__ dst, float* __restrict__ deg) {
    int e = blockIdx.x * blockDim.x + threadIdx.x;
    if (e < N_EDGES) atomicAdd(&deg[dst[e]], 1.0f);
}

__global__ void k_dinv(float* __restrict__ deg) {
    int i = blockIdx.x * blockDim.x + threadIdx.x;
    if (i < N_NODES) deg[i] = rsqrtf(deg[i] + 1.0f);
}

// ---------------- matmul1: x[100000,16] @ W1[16,128] ----------------

#define MM1_NODES 16
__global__ __launch_bounds__(256) void k_mm1(const float* __restrict__ x,
                                             const float* __restrict__ W1,
                                             float* __restrict__ out) {
    __shared__ float sw[N_FEAT][HIDDEN];        // 8 KB
    __shared__ float sx[MM1_NODES][N_FEAT + 1]; // padded
    int tid = threadIdx.x;
    int n0 = blockIdx.x * MM1_NODES;

    for (int i = tid; i < N_FEAT * HIDDEN; i += 256)
        sw[i >> 7][i & 127] = W1[i];
    if (tid < MM1_NODES * N_FEAT) {
        int n = tid >> 4, k = tid & 15;
        int gn = n0 + n;
        sx[n][k] = (gn < N_NODES) ? x[gn * N_FEAT + k] : 0.0f;
    }
    __syncthreads();

    int f = tid & 127, half = tid >> 7;  // half in {0,1} -> 8 nodes each
    float acc[8] = {0,0,0,0,0,0,0,0};
    #pragma unroll
    for (int k = 0; k < N_FEAT; ++k) {
        float w = sw[k][f];
        #pragma unroll
        for (int i = 0; i < 8; ++i)
            acc[i] += sx[half * 8 + i][k] * w;
    }
    #pragma unroll
    for (int i = 0; i < 8; ++i) {
        int gn = n0 + half * 8 + i;
        if (gn < N_NODES) out[gn * HIDDEN + f] = acc[i];
    }
}

// ---------------- edge scatter: out[dst] += h[src] * dinv[s]*dinv[d] ----------------

__global__ __launch_bounds__(256) void k_prop(const int* __restrict__ src,
                                              const int* __restrict__ dst,
                                              const float* __restrict__ dinv,
                                              const float* __restrict__ h,
                                              float* __restrict__ out) {
    int e = blockIdx.x * 2 + (threadIdx.x >> 7);
    int f = threadIdx.x & 127;
    int s = src[e], d = dst[e];
    float nrm = dinv[s] * dinv[d];
    atomicAdd(&out[d * HIDDEN + f], h[s * HIDDEN + f] * nrm);
}

// ---------------- epilogue: out = relu(out + h*dinv^2 + b) ----------------

__global__ __launch_bounds__(256) void k_epi(const float* __restrict__ hin,
                                             const float* __restrict__ dinv,
                                             const float* __restrict__ bias,
                                             float* __restrict__ out) {
    int i = blockIdx.x * blockDim.x + threadIdx.x;  // over N_NODES*HIDDEN
    int node = i >> 7, f = i & 127;
    float di = dinv[node];
    float v = out[i] + hin[i] * di * di + bias[f];
    out[i] = fmaxf(v, 0.0f);
}

// ---------------- matmul2: h[100000,128] @ W2[128,128] ----------------
// block tile: 64 nodes x 128 feats; thread tile: 8 nodes x 4 feats (256 thr)

__global__ __launch_bounds__(256) void k_mm2(const float* __restrict__ h,
                                             const float* __restrict__ W2,
                                             float* __restrict__ out) {
    __shared__ float sh[HIDDEN][72];   // transposed h tile [k][node], 36.9 KB
    __shared__ float sw[32][HIDDEN];   // W2 k-tile, 16 KB
    int tid = threadIdx.x;
    int n0 = blockIdx.x * 64;

    // stage h tile transposed: 64 nodes x 128 k
    {
        const float4* hv = (const float4*)h;
        #pragma unroll
        for (int j = 0; j < 8; ++j) {
            int q = tid + 256 * j;   // float4 index 0..2047
            int n = q >> 5;          // node 0..63
            int kq = q & 31;         // float4 index in row
            int gn = n0 + n;
            float4 v = {0.f, 0.f, 0.f, 0.f};
            if (gn < N_NODES) v = hv[gn * 32 + kq];
            int k = kq * 4;
            sh[k][n] = v.x; sh[k + 1][n] = v.y; sh[k + 2][n] = v.z; sh[k + 3][n] = v.w;
        }
    }

    int tcol = tid & 31;   // feats tcol*4 .. +4
    int trow = tid >> 5;   // nodes trow*8 .. +8
    float acc[8][4] = {};

    for (int kt = 0; kt < 4; ++kt) {
        __syncthreads();   // protects sh (first iter) and sw reuse
        {
            const float4* wv = (const float4*)(W2 + kt * 32 * HIDDEN);
            float4* swv = (float4*)(&sw[0][0]);
            #pragma unroll
            for (int j = 0; j < 4; ++j)
                swv[tid + 256 * j] = wv[tid + 256 * j];
        }
        __syncthreads();
        #pragma unroll
        for (int k = 0; k < 32; ++k) {
            int kk = kt * 32 + k;
            float4 wf = *(const float4*)(&sw[k][tcol * 4]);
            float4 a0 = *(const float4*)(&sh[kk][trow * 8]);
            float4 a1 = *(const float4*)(&sh[kk][trow * 8 + 4]);
            float av[8] = {a0.x, a0.y, a0.z, a0.w, a1.x, a1.y, a1.z, a1.w};
            #pragma unroll
            for (int i = 0; i < 8; ++i) {
                acc[i][0] += av[i] * wf.x;
                acc[i][1] += av[i] * wf.y;
                acc[i][2] += av[i] * wf.z;
                acc[i][3] += av[i] * wf.w;
            }
        }
    }

    #pragma unroll
    for (int i = 0; i < 8; ++i) {
        int gn = n0 + trow * 8 + i;
        if (gn < N_NODES) {
            float4 v = {acc[i][0], acc[i][1], acc[i][2], acc[i][3]};
            *(float4*)(&out[gn * HIDDEN + tcol * 4]) = v;
        }
    }
}

// ---------------- pooling + linear head ----------------
// out[g] = (sum_{n in g} dot(h[n], Wl)) / max(cnt,1) + bl

__global__ __launch_bounds__(256) void k_pool(const float* __restrict__ h,
                                              const int* __restrict__ batch,
                                              const float* __restrict__ Wl,
                                              const float* __restrict__ bl,
                                              float* __restrict__ out) {
    int g = blockIdx.x;
    int tid = threadIdx.x;
    __shared__ float sWl[HIDDEN];
    __shared__ float sred[4];
    if (tid < HIDDEN) sWl[tid] = Wl[tid];
    __syncthreads();

    // lower_bound(batch, g) and lower_bound(batch, g+1); batch is sorted
    int lo = 0, hi = N_NODES;
    while (lo < hi) { int mid = (lo + hi) >> 1; if (batch[mid] < g) lo = mid + 1; else hi = mid; }
    int start = lo;
    hi = N_NODES;
    while (lo < hi) { int mid = (lo + hi) >> 1; if (batch[mid] < g + 1) lo = mid + 1; else hi = mid; }
    int end = lo;

    int f = tid & 127;
    float w = sWl[f];
    float acc = 0.0f;
    for (int n = start + (tid >> 7); n < end; n += 2)
        acc += h[n * HIDDEN + f] * w;

    // wave64 reduce then cross-wave via LDS
    #pragma unroll
    for (int off = 32; off; off >>= 1) acc += __shfl_down(acc, off, 64);
    int wave = tid >> 6, lane = tid & 63;
    if (lane == 0) sred[wave] = acc;
    __syncthreads();
    if (tid == 0) {
        float s = sred[0] + sred[1] + sred[2] + sred[3];
        float cnt = (float)(end - start);
        out[g] = s / fmaxf(cnt, 1.0f) + bl[0];
    }
}

// ---------------- launch ----------------

extern "C" void kernel_launch(void* const* d_in, const int* in_sizes, int n_in,
                              void* d_out, int out_size, void* d_ws, size_t ws_size,
                              hipStream_t stream) {
    const float* x    = (const float*)d_in[0];
    const int*   src  = (const int*)d_in[1];
    const int*   dst  = src + N_EDGES;
    const int*   batch= (const int*)d_in[2];
    const float* W1   = (const float*)d_in[3];
    const float* b1   = (const float*)d_in[4];
    const float* W2   = (const float*)d_in[5];
    const float* b2   = (const float*)d_in[6];
    const float* Wl   = (const float*)d_in[7];
    const float* bl   = (const float*)d_in[8];
    float* out = (float*)d_out;

    const size_t NH = (size_t)N_NODES * HIDDEN;
    float* f0   = (float*)d_ws;        // matmul outputs (h)
    float* f1   = f0 + NH;             // scatter accumulators / layer outputs
    float* dinv = f1 + NH;             // degree then dinv, N_NODES floats

    // degree -> dinv (shared by both layers)
    hipMemsetAsync(dinv, 0, N_NODES * sizeof(float), stream);
    k_deg<<<(N_EDGES + 255) / 256, 256, 0, stream>>>(dst, dinv);
    k_dinv<<<(N_NODES + 255) / 256, 256, 0, stream>>>(dinv);

    // layer 1
    k_mm1<<<(N_NODES + MM1_NODES - 1) / MM1_NODES, 256, 0, stream>>>(x, W1, f0);
    hipMemsetAsync(f1, 0, NH * sizeof(float), stream);
    k_prop<<<N_EDGES / 2, 256, 0, stream>>>(src, dst, dinv, f0, f1);
    k_epi<<<(int)(NH / 256), 256, 0, stream>>>(f0, dinv, b1, f1);

    // layer 2
    k_mm2<<<(N_NODES + 63) / 64, 256, 0, stream>>>(f1, W2, f0);
    hipMemsetAsync(f1, 0, NH * sizeof(float), stream);
    k_prop<<<N_EDGES / 2, 256, 0, stream>>>(src, dst, dinv, f0, f1);
    k_epi<<<(int)(NH / 256), 256, 0, stream>>>(f0, dinv, b2, f1);

    // pool + head
    k_pool<<<N_GRAPHS, 256, 0, stream>>>(f1, batch, Wl, bl, out);
}

// Round 2
// 591.139 us; speedup vs baseline: 2.9304x; 2.9304x over previous
//
#include <hip/hip_runtime.h>

#define N_NODES 100000
#define N_EDGES 1600000
#define N_FEAT  16
#define HIDDEN  128
#define N_GRAPHS 512
#define NB_SCAN 391   // ceil(N_NODES/256)

// ---------------- degree count ----------------

__global__ void k_deg(const int* __restrict__ dst, int* __restrict__ cnt) {
    int e = blockIdx.x * blockDim.x + threadIdx.x;
    if (e < N_EDGES) atomicAdd(&cnt[dst[e]], 1);
}

// ---------------- exclusive scan over cnt -> rowptr (3 phases) ----------------

__device__ __forceinline__ int wave_incl_scan(int v) {
    int lane = threadIdx.x & 63;
    #pragma unroll
    for (int off = 1; off < 64; off <<= 1) {
        int u = __shfl_up(v, off, 64);
        if (lane >= off) v += u;
    }
    return v;
}

__global__ __launch_bounds__(256) void k_bsum(const int* __restrict__ cnt,
                                              int* __restrict__ bsum) {
    int i = blockIdx.x * 256 + threadIdx.x;
    int v = (i < N_NODES) ? cnt[i] : 0;
    #pragma unroll
    for (int off = 32; off; off >>= 1) v += __shfl_down(v, off, 64);
    __shared__ int ws[4];
    int wave = threadIdx.x >> 6, lane = threadIdx.x & 63;
    if (lane == 0) ws[wave] = v;
    __syncthreads();
    if (threadIdx.x == 0) bsum[blockIdx.x] = ws[0] + ws[1] + ws[2] + ws[3];
}

__global__ __launch_bounds__(512) void k_scanb(const int* __restrict__ bsum,
                                               int* __restrict__ boff) {
    int tid = threadIdx.x;
    int v = (tid < NB_SCAN) ? bsum[tid] : 0;
    int incl = wave_incl_scan(v);
    __shared__ int ws[8];
    int wave = tid >> 6, lane = tid & 63;
    if (lane == 63) ws[wave] = incl;
    __syncthreads();
    int add = 0;
    for (int w = 0; w < wave; ++w) add += ws[w];
    if (tid < NB_SCAN) boff[tid] = add + incl - v;
}

__global__ __launch_bounds__(256) void k_scanf(const int* __restrict__ cnt,
                                               const int* __restrict__ boff,
                                               int* __restrict__ rowptr,
                                               int* __restrict__ cursor) {
    int tid = threadIdx.x;
    int i = blockIdx.x * 256 + tid;
    int v = (i < N_NODES) ? cnt[i] : 0;
    int incl = wave_incl_scan(v);
    __shared__ int ws[4];
    int wave = tid >> 6, lane = tid & 63;
    if (lane == 63) ws[wave] = incl;
    __syncthreads();
    int add = boff[blockIdx.x];
    for (int w = 0; w < wave; ++w) add += ws[w];
    int excl = add + incl - v;
    if (i < N_NODES) { rowptr[i] = excl; cursor[i] = excl; }
    if (i == N_NODES - 1) rowptr[N_NODES] = excl + v;
}

// ---------------- dinv from rowptr ----------------

__global__ void k_dinv(const int* __restrict__ rowptr, float* __restrict__ dinv) {
    int i = blockIdx.x * blockDim.x + threadIdx.x;
    if (i < N_NODES)
        dinv[i] = rsqrtf((float)(rowptr[i + 1] - rowptr[i]) + 1.0f);
}

// ---------------- bucket edges by dst ----------------

__global__ void k_bucket(const int* __restrict__ src, const int* __restrict__ dst,
                         int* __restrict__ cursor, int* __restrict__ esrc) {
    int e = blockIdx.x * blockDim.x + threadIdx.x;
    if (e < N_EDGES) {
        int d = dst[e];
        int p = atomicAdd(&cursor[d], 1);
        esrc[p] = src[e];
    }
}

// ---------------- layer-1 aggregation in 16-dim ----------------
// agg16[d] = x[d]*dinv[d]^2 + sum_e dinv[s]*dinv[d]*x[s]

__global__ __launch_bounds__(256) void k_agg1(const int* __restrict__ rowptr,
                                              const int* __restrict__ esrc,
                                              const float* __restrict__ dinv,
                                              const float* __restrict__ x,
                                              float* __restrict__ agg16) {
    int node = blockIdx.x * 16 + (threadIdx.x >> 4);
    int f = threadIdx.x & 15;
    int beg = rowptr[node], end = rowptr[node + 1];
    float dd = dinv[node];
    float acc = x[node * N_FEAT + f] * dd * dd;
    for (int j = beg; j < end; ++j) {
        int s = esrc[j];
        acc += x[s * N_FEAT + f] * (dinv[s] * dd);
    }
    agg16[node * N_FEAT + f] = acc;
}

// ---------------- mm1: h1 = relu(agg16 @ W1 + b1) ----------------

#define MM1_NODES 16
__global__ __launch_bounds__(256) void k_mm1b(const float* __restrict__ a,
                                              const float* __restrict__ W1,
                                              const float* __restrict__ b1,
                                              float* __restrict__ out) {
    __shared__ float sw[N_FEAT][HIDDEN];
    __shared__ float sx[MM1_NODES][N_FEAT + 1];
    int tid = threadIdx.x;
    int n0 = blockIdx.x * MM1_NODES;

    for (int i = tid; i < N_FEAT * HIDDEN; i += 256)
        sw[i >> 7][i & 127] = W1[i];
    if (tid < MM1_NODES * N_FEAT) {
        int n = tid >> 4, k = tid & 15;
        sx[n][k] = a[(n0 + n) * N_FEAT + k];
    }
    __syncthreads();

    int f = tid & 127, half = tid >> 7;
    float bias = b1[f];
    float acc[8] = {0,0,0,0,0,0,0,0};
    #pragma unroll
    for (int k = 0; k < N_FEAT; ++k) {
        float w = sw[k][f];
        #pragma unroll
        for (int i = 0; i < 8; ++i)
            acc[i] += sx[half * 8 + i][k] * w;
    }
    #pragma unroll
    for (int i = 0; i < 8; ++i)
        out[(n0 + half * 8 + i) * HIDDEN + f] = fmaxf(acc[i] + bias, 0.0f);
}

// ---------------- layer-2 aggregation in 128-dim (1 wave / node) ----------------

__global__ __launch_bounds__(256) void k_agg2(const int* __restrict__ rowptr,
                                              const int* __restrict__ esrc,
                                              const float* __restrict__ dinv,
                                              const float* __restrict__ h1,
                                              float* __restrict__ agg2) {
    int node = blockIdx.x * 4 + (threadIdx.x >> 6);
    int f2 = threadIdx.x & 63;  // float2 lane
    const float2* h = (const float2*)h1;
    int beg = rowptr[node], end = rowptr[node + 1];
    float dd = dinv[node];
    float2 self = h[node * 64 + f2];
    float2 acc = { self.x * dd * dd, self.y * dd * dd };
    for (int j = beg; j < end; ++j) {
        int s = esrc[j];
        float nrm = dinv[s] * dd;
        float2 v = h[s * 64 + f2];
        acc.x += v.x * nrm;
        acc.y += v.y * nrm;
    }
    ((float2*)agg2)[node * 64 + f2] = acc;
}

// ---------------- mm2 fused head: snode[n] = dot(relu(agg2[n]@W2 + b2), Wl) ----------------

__global__ __launch_bounds__(256) void k_mm2s(const float* __restrict__ h,
                                              const float* __restrict__ W2,
                                              const float* __restrict__ b2,
                                              const float* __restrict__ Wl,
                                              float* __restrict__ snode) {
    __shared__ float sh[HIDDEN][72];   // transposed h tile [k][node]
    __shared__ float sw[32][HIDDEN];   // W2 k-tile
    int tid = threadIdx.x;
    int n0 = blockIdx.x * 64;

    {
        const float4* hv = (const float4*)h;
        #pragma unroll
        for (int j = 0; j < 8; ++j) {
            int q = tid + 256 * j;
            int n = q >> 5;
            int kq = q & 31;
            int gn = n0 + n;
            float4 v = {0.f, 0.f, 0.f, 0.f};
            if (gn < N_NODES) v = hv[gn * 32 + kq];
            int k = kq * 4;
            sh[k][n] = v.x; sh[k + 1][n] = v.y; sh[k + 2][n] = v.z; sh[k + 3][n] = v.w;
        }
    }

    int tcol = tid & 31;
    int trow = tid >> 5;
    float acc[8][4] = {};

    for (int kt = 0; kt < 4; ++kt) {
        __syncthreads();
        {
            const float4* wv = (const float4*)(W2 + kt * 32 * HIDDEN);
            float4* swv = (float4*)(&sw[0][0]);
            #pragma unroll
            for (int j = 0; j < 4; ++j)
                swv[tid + 256 * j] = wv[tid + 256 * j];
        }
        __syncthreads();
        #pragma unroll
        for (int k = 0; k < 32; ++k) {
            int kk = kt * 32 + k;
            float4 wf = *(const float4*)(&sw[k][tcol * 4]);
            float4 a0 = *(const float4*)(&sh[kk][trow * 8]);
            float4 a1 = *(const float4*)(&sh[kk][trow * 8 + 4]);
            float av[8] = {a0.x, a0.y, a0.z, a0.w, a1.x, a1.y, a1.z, a1.w};
            #pragma unroll
            for (int i = 0; i < 8; ++i) {
                acc[i][0] += av[i] * wf.x;
                acc[i][1] += av[i] * wf.y;
                acc[i][2] += av[i] * wf.z;
                acc[i][3] += av[i] * wf.w;
            }
        }
    }

    // epilogue: bias + relu + dot(Wl), reduce across 32 tcol lanes
    float4 bv = *(const float4*)(&b2[tcol * 4]);
    float4 wlv = *(const float4*)(&Wl[tcol * 4]);
    float bb[4] = {bv.x, bv.y, bv.z, bv.w};
    float wl[4] = {wlv.x, wlv.y, wlv.z, wlv.w};
    #pragma unroll
    for (int i = 0; i < 8; ++i) {
        float part = 0.0f;
        #pragma unroll
        for (int c = 0; c < 4; ++c)
            part += fmaxf(acc[i][c] + bb[c], 0.0f) * wl[c];
        #pragma unroll
        for (int off = 16; off; off >>= 1)
            part += __shfl_down(part, off, 32);
        int gn = n0 + trow * 8 + i;
        if (tcol == 0 && gn < N_NODES) snode[gn] = part;
    }
}

// ---------------- pooling: out[g] = mean(snode over graph g) + bl ----------------

__global__ __launch_bounds__(256) void k_pool(const float* __restrict__ snode,
                                              const int* __restrict__ batch,
                                              const float* __restrict__ bl,
                                              float* __restrict__ out) {
    int g = blockIdx.x;
    int tid = threadIdx.x;
    __shared__ float sred[4];

    int lo = 0, hi = N_NODES;
    while (lo < hi) { int mid = (lo + hi) >> 1; if (batch[mid] < g) lo = mid + 1; else hi = mid; }
    int start = lo;
    hi = N_NODES;
    while (lo < hi) { int mid = (lo + hi) >> 1; if (batch[mid] < g + 1) lo = mid + 1; else hi = mid; }
    int end = lo;

    float acc = 0.0f;
    for (int n = start + tid; n < end; n += 256) acc += snode[n];

    #pragma unroll
    for (int off = 32; off; off >>= 1) acc += __shfl_down(acc, off, 64);
    int wave = tid >> 6, lane = tid & 63;
    if (lane == 0) sred[wave] = acc;
    __syncthreads();
    if (tid == 0) {
        float s = sred[0] + sred[1] + sred[2] + sred[3];
        float cnt = (float)(end - start);
        out[g] = s / fmaxf(cnt, 1.0f) + bl[0];
    }
}

// ---------------- launch ----------------

extern "C" void kernel_launch(void* const* d_in, const int* in_sizes, int n_in,
                              void* d_out, int out_size, void* d_ws, size_t ws_size,
                              hipStream_t stream) {
    const float* x    = (const float*)d_in[0];
    const int*   src  = (const int*)d_in[1];
    const int*   dst  = src + N_EDGES;
    const int*   batch= (const int*)d_in[2];
    const float* W1   = (const float*)d_in[3];
    const float* b1   = (const float*)d_in[4];
    const float* W2   = (const float*)d_in[5];
    const float* b2   = (const float*)d_in[6];
    const float* Wl   = (const float*)d_in[7];
    const float* bl   = (const float*)d_in[8];
    float* out = (float*)d_out;

    const size_t NH = (size_t)N_NODES * HIDDEN;

    float* h1    = (float*)d_ws;           // NH
    float* agg2  = h1 + NH;                // NH (agg16 aliases front of this)
    float* agg16 = agg2;                   // N_NODES*16, dead before agg2 written
    float* dinv  = agg2 + NH;              // N_NODES
    float* snode = dinv + N_NODES;         // N_NODES
    int*   cnt    = (int*)(snode + N_NODES);  // N_NODES
    int*   rowptr = cnt + N_NODES;            // N_NODES+1
    int*   cursor = rowptr + N_NODES + 1;     // N_NODES
    int*   bsum   = cursor + N_NODES;         // NB_SCAN
    int*   boff   = bsum + NB_SCAN;           // NB_SCAN
    int*   esrc   = boff + NB_SCAN;           // N_EDGES

    // CSR build
    hipMemsetAsync(cnt, 0, N_NODES * sizeof(int), stream);
    k_deg<<<(N_EDGES + 255) / 256, 256, 0, stream>>>(dst, cnt);
    k_bsum<<<NB_SCAN, 256, 0, stream>>>(cnt, bsum);
    k_scanb<<<1, 512, 0, stream>>>(bsum, boff);
    k_scanf<<<NB_SCAN, 256, 0, stream>>>(cnt, boff, rowptr, cursor);
    k_dinv<<<(N_NODES + 255) / 256, 256, 0, stream>>>(rowptr, dinv);
    k_bucket<<<(N_EDGES + 255) / 256, 256, 0, stream>>>(src, dst, cursor, esrc);

    // layer 1: aggregate in 16-dim, then matmul
    k_agg1<<<N_NODES / 16, 256, 0, stream>>>(rowptr, esrc, dinv, x, agg16);
    k_mm1b<<<N_NODES / MM1_NODES, 256, 0, stream>>>(agg16, W1, b1, h1);

    // layer 2: aggregate 128-dim, fused mm2 + head dot
    k_agg2<<<N_NODES / 4, 256, 0, stream>>>(rowptr, esrc, dinv, h1, agg2);
    k_mm2s<<<(N_NODES + 63) / 64, 256, 0, stream>>>(agg2, W2, b2, Wl, snode);

    // pool + bias
    k_pool<<<N_GRAPHS, 256, 0, stream>>>(snode, batch, bl, out);
}

// Round 3
// 537.321 us; speedup vs baseline: 3.2240x; 1.1002x over previous
//
#include <hip/hip_runtime.h>

#define N_NODES 100000
#define N_EDGES 1600000
#define N_FEAT  16
#define HIDDEN  128
#define N_GRAPHS 512
#define NB_SCAN 391   // ceil(N_NODES/256)

// ---------------- degree count ----------------

__global__ void k_deg(const int* __restrict__ dst, int* __restrict__ cnt) {
    int e = blockIdx.x * blockDim.x + threadIdx.x;
    if (e < N_EDGES) atomicAdd(&cnt[dst[e]], 1);
}

// ---------------- exclusive scan over cnt -> rowptr (3 phases) ----------------

__device__ __forceinline__ int wave_incl_scan(int v) {
    int lane = threadIdx.x & 63;
    #pragma unroll
    for (int off = 1; off < 64; off <<= 1) {
        int u = __shfl_up(v, off, 64);
        if (lane >= off) v += u;
    }
    return v;
}

__global__ __launch_bounds__(256) void k_bsum(const int* __restrict__ cnt,
                                              int* __restrict__ bsum) {
    int i = blockIdx.x * 256 + threadIdx.x;
    int v = (i < N_NODES) ? cnt[i] : 0;
    #pragma unroll
    for (int off = 32; off; off >>= 1) v += __shfl_down(v, off, 64);
    __shared__ int ws[4];
    int wave = threadIdx.x >> 6, lane = threadIdx.x & 63;
    if (lane == 0) ws[wave] = v;
    __syncthreads();
    if (threadIdx.x == 0) bsum[blockIdx.x] = ws[0] + ws[1] + ws[2] + ws[3];
}

__global__ __launch_bounds__(512) void k_scanb(const int* __restrict__ bsum,
                                               int* __restrict__ boff) {
    int tid = threadIdx.x;
    int v = (tid < NB_SCAN) ? bsum[tid] : 0;
    int incl = wave_incl_scan(v);
    __shared__ int ws[8];
    int wave = tid >> 6, lane = tid & 63;
    if (lane == 63) ws[wave] = incl;
    __syncthreads();
    int add = 0;
    for (int w = 0; w < wave; ++w) add += ws[w];
    if (tid < NB_SCAN) boff[tid] = add + incl - v;
}

__global__ __launch_bounds__(256) void k_scanf(const int* __restrict__ cnt,
                                               const int* __restrict__ boff,
                                               int* __restrict__ rowptr,
                                               int* __restrict__ cursor) {
    int tid = threadIdx.x;
    int i = blockIdx.x * 256 + tid;
    int v = (i < N_NODES) ? cnt[i] : 0;
    int incl = wave_incl_scan(v);
    __shared__ int ws[4];
    int wave = tid >> 6, lane = tid & 63;
    if (lane == 63) ws[wave] = incl;
    __syncthreads();
    int add = boff[blockIdx.x];
    for (int w = 0; w < wave; ++w) add += ws[w];
    int excl = add + incl - v;
    if (i < N_NODES) { rowptr[i] = excl; cursor[i] = excl; }
    if (i == N_NODES - 1) rowptr[N_NODES] = excl + v;
}

// ---------------- dinv from rowptr ----------------

__global__ void k_dinv(const int* __restrict__ rowptr, float* __restrict__ dinv) {
    int i = blockIdx.x * blockDim.x + threadIdx.x;
    if (i < N_NODES)
        dinv[i] = rsqrtf((float)(rowptr[i + 1] - rowptr[i]) + 1.0f);
}

// ---------------- bucket edges by dst ----------------

__global__ void k_bucket(const int* __restrict__ src, const int* __restrict__ dst,
                         int* __restrict__ cursor, int* __restrict__ esrc) {
    int e = blockIdx.x * blockDim.x + threadIdx.x;
    if (e < N_EDGES) {
        int d = dst[e];
        int p = atomicAdd(&cursor[d], 1);
        esrc[p] = src[e];
    }
}

// ---------------- layer-1 aggregation in 16-dim ----------------
// 1 wave per node; lanes = 4 edge-groups x 16 feats. Unroll x2 -> up to 8
// row-gathers in flight per wave.

__global__ __launch_bounds__(256) void k_agg1(const int* __restrict__ rowptr,
                                              const int* __restrict__ esrc,
                                              const float* __restrict__ dinv,
                                              const float* __restrict__ x,
                                              float* __restrict__ agg16) {
    int tid = threadIdx.x;
    int wave = tid >> 6;
    int lane = tid & 63;
    int e = lane >> 4;       // edge group 0..3
    int f = lane & 15;       // feature
    int node = blockIdx.x * 4 + wave;
    int beg = rowptr[node], end = rowptr[node + 1];
    float dd = dinv[node];

    float acc = 0.0f;
    int j = beg + e;
    for (; j + 4 < end; j += 8) {
        int sA = esrc[j];     float wA = dinv[sA] * dd;
        int sB = esrc[j + 4]; float wB = dinv[sB] * dd;
        float vA = x[sA * N_FEAT + f];
        float vB = x[sB * N_FEAT + f];
        acc += vA * wA + vB * wB;
    }
    if (j < end) {
        int s = esrc[j];
        acc += x[s * N_FEAT + f] * (dinv[s] * dd);
    }
    // reduce the 4 edge-groups (lanes differing in bits 4,5)
    acc += __shfl_xor(acc, 16, 64);
    acc += __shfl_xor(acc, 32, 64);
    if (e == 0)
        agg16[node * N_FEAT + f] = acc + x[node * N_FEAT + f] * dd * dd;
}

// ---------------- mm1: h1 = relu(agg16 @ W1 + b1) ----------------

#define MM1_NODES 16
__global__ __launch_bounds__(256) void k_mm1b(const float* __restrict__ a,
                                              const float* __restrict__ W1,
                                              const float* __restrict__ b1,
                                              float* __restrict__ out) {
    __shared__ float sw[N_FEAT][HIDDEN];
    __shared__ float sx[MM1_NODES][N_FEAT + 1];
    int tid = threadIdx.x;
    int n0 = blockIdx.x * MM1_NODES;

    for (int i = tid; i < N_FEAT * HIDDEN; i += 256)
        sw[i >> 7][i & 127] = W1[i];
    if (tid < MM1_NODES * N_FEAT) {
        int n = tid >> 4, k = tid & 15;
        sx[n][k] = a[(n0 + n) * N_FEAT + k];
    }
    __syncthreads();

    int f = tid & 127, half = tid >> 7;
    float bias = b1[f];
    float acc[8] = {0,0,0,0,0,0,0,0};
    #pragma unroll
    for (int k = 0; k < N_FEAT; ++k) {
        float w = sw[k][f];
        #pragma unroll
        for (int i = 0; i < 8; ++i)
            acc[i] += sx[half * 8 + i][k] * w;
    }
    #pragma unroll
    for (int i = 0; i < 8; ++i)
        out[(n0 + half * 8 + i) * HIDDEN + f] = fmaxf(acc[i] + bias, 0.0f);
}

// ---------------- layer-2 aggregation in 128-dim ----------------
// 32 lanes per node, float4/lane; inner loop unrolled x4 -> 4 row-gathers
// (+4 dinv broadcasts) in flight per wave.

__global__ __launch_bounds__(256) void k_agg2(const int* __restrict__ rowptr,
                                              const int* __restrict__ esrc,
                                              const float* __restrict__ dinv,
                                              const float* __restrict__ h1,
                                              float* __restrict__ agg2) {
    int tid = threadIdx.x;
    int sub = tid >> 5;      // 0..7 node within block
    int l32 = tid & 31;      // float4 lane within node row
    int node = blockIdx.x * 8 + sub;
    const float4* h4 = (const float4*)h1;
    int beg = rowptr[node], end = rowptr[node + 1];
    float dd = dinv[node];
    float4 self = h4[node * 32 + l32];
    float4 acc = { self.x * dd * dd, self.y * dd * dd,
                   self.z * dd * dd, self.w * dd * dd };

    int j = beg;
    for (; j + 4 <= end; j += 4) {
        int s0 = esrc[j], s1 = esrc[j + 1], s2 = esrc[j + 2], s3 = esrc[j + 3];
        float w0 = dinv[s0] * dd, w1 = dinv[s1] * dd,
              w2 = dinv[s2] * dd, w3 = dinv[s3] * dd;
        float4 v0 = h4[s0 * 32 + l32];
        float4 v1 = h4[s1 * 32 + l32];
        float4 v2 = h4[s2 * 32 + l32];
        float4 v3 = h4[s3 * 32 + l32];
        acc.x += v0.x * w0 + v1.x * w1 + v2.x * w2 + v3.x * w3;
        acc.y += v0.y * w0 + v1.y * w1 + v2.y * w2 + v3.y * w3;
        acc.z += v0.z * w0 + v1.z * w1 + v2.z * w2 + v3.z * w3;
        acc.w += v0.w * w0 + v1.w * w1 + v2.w * w2 + v3.w * w3;
    }
    for (; j < end; ++j) {
        int s = esrc[j];
        float w = dinv[s] * dd;
        float4 v = h4[s * 32 + l32];
        acc.x += v.x * w; acc.y += v.y * w; acc.z += v.z * w; acc.w += v.w * w;
    }
    ((float4*)agg2)[node * 32 + l32] = acc;
}

// ---------------- mm2 fused head: snode[n] = dot(relu(agg2[n]@W2 + b2), Wl) ----------------

__global__ __launch_bounds__(256) void k_mm2s(const float* __restrict__ h,
                                              const float* __restrict__ W2,
                                              const float* __restrict__ b2,
                                              const float* __restrict__ Wl,
                                              float* __restrict__ snode) {
    __shared__ float sh[HIDDEN][72];   // transposed h tile [k][node]
    __shared__ float sw[32][HIDDEN];   // W2 k-tile
    int tid = threadIdx.x;
    int n0 = blockIdx.x * 64;

    {
        const float4* hv = (const float4*)h;
        #pragma unroll
        for (int j = 0; j < 8; ++j) {
            int q = tid + 256 * j;
            int n = q >> 5;
            int kq = q & 31;
            int gn = n0 + n;
            float4 v = {0.f, 0.f, 0.f, 0.f};
            if (gn < N_NODES) v = hv[gn * 32 + kq];
            int k = kq * 4;
            sh[k][n] = v.x; sh[k + 1][n] = v.y; sh[k + 2][n] = v.z; sh[k + 3][n] = v.w;
        }
    }

    int tcol = tid & 31;
    int trow = tid >> 5;
    float acc[8][4] = {};

    for (int kt = 0; kt < 4; ++kt) {
        __syncthreads();
        {
            const float4* wv = (const float4*)(W2 + kt * 32 * HIDDEN);
            float4* swv = (float4*)(&sw[0][0]);
            #pragma unroll
            for (int j = 0; j < 4; ++j)
                swv[tid + 256 * j] = wv[tid + 256 * j];
        }
        __syncthreads();
        #pragma unroll
        for (int k = 0; k < 32; ++k) {
            int kk = kt * 32 + k;
            float4 wf = *(const float4*)(&sw[k][tcol * 4]);
            float4 a0 = *(const float4*)(&sh[kk][trow * 8]);
            float4 a1 = *(const float4*)(&sh[kk][trow * 8 + 4]);
            float av[8] = {a0.x, a0.y, a0.z, a0.w, a1.x, a1.y, a1.z, a1.w};
            #pragma unroll
            for (int i = 0; i < 8; ++i) {
                acc[i][0] += av[i] * wf.x;
                acc[i][1] += av[i] * wf.y;
                acc[i][2] += av[i] * wf.z;
                acc[i][3] += av[i] * wf.w;
            }
        }
    }

    float4 bv = *(const float4*)(&b2[tcol * 4]);
    float4 wlv = *(const float4*)(&Wl[tcol * 4]);
    float bb[4] = {bv.x, bv.y, bv.z, bv.w};
    float wl[4] = {wlv.x, wlv.y, wlv.z, wlv.w};
    #pragma unroll
    for (int i = 0; i < 8; ++i) {
        float part = 0.0f;
        #pragma unroll
        for (int c = 0; c < 4; ++c)
            part += fmaxf(acc[i][c] + bb[c], 0.0f) * wl[c];
        #pragma unroll
        for (int off = 16; off; off >>= 1)
            part += __shfl_down(part, off, 32);
        int gn = n0 + trow * 8 + i;
        if (tcol == 0 && gn < N_NODES) snode[gn] = part;
    }
}

// ---------------- pooling: out[g] = mean(snode over graph g) + bl ----------------

__global__ __launch_bounds__(256) void k_pool(const float* __restrict__ snode,
                                              const int* __restrict__ batch,
                                              const float* __restrict__ bl,
                                              float* __restrict__ out) {
    int g = blockIdx.x;
    int tid = threadIdx.x;
    __shared__ float sred[4];

    int lo = 0, hi = N_NODES;
    while (lo < hi) { int mid = (lo + hi) >> 1; if (batch[mid] < g) lo = mid + 1; else hi = mid; }
    int start = lo;
    hi = N_NODES;
    while (lo < hi) { int mid = (lo + hi) >> 1; if (batch[mid] < g + 1) lo = mid + 1; else hi = mid; }
    int end = lo;

    float acc = 0.0f;
    for (int n = start + tid; n < end; n += 256) acc += snode[n];

    #pragma unroll
    for (int off = 32; off; off >>= 1) acc += __shfl_down(acc, off, 64);
    int wave = tid >> 6, lane = tid & 63;
    if (lane == 0) sred[wave] = acc;
    __syncthreads();
    if (tid == 0) {
        float s = sred[0] + sred[1] + sred[2] + sred[3];
        float cnt = (float)(end - start);
        out[g] = s / fmaxf(cnt, 1.0f) + bl[0];
    }
}

// ---------------- launch ----------------

extern "C" void kernel_launch(void* const* d_in, const int* in_sizes, int n_in,
                              void* d_out, int out_size, void* d_ws, size_t ws_size,
                              hipStream_t stream) {
    const float* x    = (const float*)d_in[0];
    const int*   src  = (const int*)d_in[1];
    const int*   dst  = src + N_EDGES;
    const int*   batch= (const int*)d_in[2];
    const float* W1   = (const float*)d_in[3];
    const float* b1   = (const float*)d_in[4];
    const float* W2   = (const float*)d_in[5];
    const float* b2   = (const float*)d_in[6];
    const float* Wl   = (const float*)d_in[7];
    const float* bl   = (const float*)d_in[8];
    float* out = (float*)d_out;

    const size_t NH = (size_t)N_NODES * HIDDEN;

    float* h1    = (float*)d_ws;           // NH
    float* agg2  = h1 + NH;                // NH (agg16 aliases front of this)
    float* agg16 = agg2;                   // N_NODES*16, dead before agg2 written
    float* dinv  = agg2 + NH;              // N_NODES
    float* snode = dinv + N_NODES;         // N_NODES
    int*   cnt    = (int*)(snode + N_NODES);  // N_NODES
    int*   rowptr = cnt + N_NODES;            // N_NODES+1
    int*   cursor = rowptr + N_NODES + 1;     // N_NODES
    int*   bsum   = cursor + N_NODES;         // NB_SCAN
    int*   boff   = bsum + NB_SCAN;           // NB_SCAN
    int*   esrc   = boff + NB_SCAN;           // N_EDGES

    // CSR build
    hipMemsetAsync(cnt, 0, N_NODES * sizeof(int), stream);
    k_deg<<<(N_EDGES + 255) / 256, 256, 0, stream>>>(dst, cnt);
    k_bsum<<<NB_SCAN, 256, 0, stream>>>(cnt, bsum);
    k_scanb<<<1, 512, 0, stream>>>(bsum, boff);
    k_scanf<<<NB_SCAN, 256, 0, stream>>>(cnt, boff, rowptr, cursor);
    k_dinv<<<(N_NODES + 255) / 256, 256, 0, stream>>>(rowptr, dinv);
    k_bucket<<<(N_EDGES + 255) / 256, 256, 0, stream>>>(src, dst, cursor, esrc);

    // layer 1: aggregate in 16-dim, then matmul
    k_agg1<<<N_NODES / 4, 256, 0, stream>>>(rowptr, esrc, dinv, x, agg16);
    k_mm1b<<<N_NODES / MM1_NODES, 256, 0, stream>>>(agg16, W1, b1, h1);

    // layer 2: aggregate 128-dim, fused mm2 + head dot
    k_agg2<<<N_NODES / 8, 256, 0, stream>>>(rowptr, esrc, dinv, h1, agg2);
    k_mm2s<<<(N_NODES + 63) / 64, 256, 0, stream>>>(agg2, W2, b2, Wl, snode);

    // pool + bias
    k_pool<<<N_GRAPHS, 256, 0, stream>>>(snode, batch, bl, out);
}

// Round 4
// 387.181 us; speedup vs baseline: 4.4741x; 1.3878x over previous
//
#include <hip/hip_runtime.h>
#include <hip/hip_bf16.h>

#define N_NODES 100000
#define N_EDGES 1600000
#define N_FEAT  16
#define HIDDEN  128
#define N_GRAPHS 512
#define NB_SCAN 391   // ceil(N_NODES/256)

typedef unsigned short ushort_t;

// ---------------- degree count + rank capture ----------------

__global__ void k_deg(const int* __restrict__ dst, int* __restrict__ cnt,
                      int* __restrict__ rank) {
    int e = blockIdx.x * blockDim.x + threadIdx.x;
    if (e < N_EDGES) rank[e] = atomicAdd(&cnt[dst[e]], 1);
}

// ---------------- exclusive scan over cnt -> rowptr (3 phases) ----------------

__device__ __forceinline__ int wave_incl_scan(int v) {
    int lane = threadIdx.x & 63;
    #pragma unroll
    for (int off = 1; off < 64; off <<= 1) {
        int u = __shfl_up(v, off, 64);
        if (lane >= off) v += u;
    }
    return v;
}

__global__ __launch_bounds__(256) void k_bsum(const int* __restrict__ cnt,
                                              int* __restrict__ bsum) {
    int i = blockIdx.x * 256 + threadIdx.x;
    int v = (i < N_NODES) ? cnt[i] : 0;
    #pragma unroll
    for (int off = 32; off; off >>= 1) v += __shfl_down(v, off, 64);
    __shared__ int ws[4];
    int wave = threadIdx.x >> 6, lane = threadIdx.x & 63;
    if (lane == 0) ws[wave] = v;
    __syncthreads();
    if (threadIdx.x == 0) bsum[blockIdx.x] = ws[0] + ws[1] + ws[2] + ws[3];
}

__global__ __launch_bounds__(512) void k_scanb(const int* __restrict__ bsum,
                                               int* __restrict__ boff) {
    int tid = threadIdx.x;
    int v = (tid < NB_SCAN) ? bsum[tid] : 0;
    int incl = wave_incl_scan(v);
    __shared__ int ws[8];
    int wave = tid >> 6, lane = tid & 63;
    if (lane == 63) ws[wave] = incl;
    __syncthreads();
    int add = 0;
    for (int w = 0; w < wave; ++w) add += ws[w];
    if (tid < NB_SCAN) boff[tid] = add + incl - v;
}

__global__ __launch_bounds__(256) void k_scanf(const int* __restrict__ cnt,
                                               const int* __restrict__ boff,
                                               int* __restrict__ rowptr,
                                               float* __restrict__ dinv) {
    int tid = threadIdx.x;
    int i = blockIdx.x * 256 + tid;
    int v = (i < N_NODES) ? cnt[i] : 0;
    int incl = wave_incl_scan(v);
    __shared__ int ws[4];
    int wave = tid >> 6, lane = tid & 63;
    if (lane == 63) ws[wave] = incl;
    __syncthreads();
    int add = boff[blockIdx.x];
    for (int w = 0; w < wave; ++w) add += ws[w];
    int excl = add + incl - v;
    if (i < N_NODES) {
        rowptr[i] = excl;
        dinv[i] = rsqrtf((float)v + 1.0f);
    }
    if (i == N_NODES - 1) rowptr[N_NODES] = excl + v;
}

// ---------------- bucket edges by dst (atomic-free) ----------------

__global__ void k_bucket(const int* __restrict__ src, const int* __restrict__ dst,
                         const int* __restrict__ rank, const int* __restrict__ rowptr,
                         int* __restrict__ esrc) {
    int e = blockIdx.x * blockDim.x + threadIdx.x;
    if (e < N_EDGES)
        esrc[rowptr[dst[e]] + rank[e]] = src[e];
}

// ---------------- layer-1 aggregation in 16-dim ----------------
// 1 wave per node; lanes = 4 edge-groups x 16 feats, unroll x2.

__global__ __launch_bounds__(256) void k_agg1(const int* __restrict__ rowptr,
                                              const int* __restrict__ esrc,
                                              const float* __restrict__ dinv,
                                              const float* __restrict__ x,
                                              float* __restrict__ agg16) {
    int tid = threadIdx.x;
    int wave = tid >> 6;
    int lane = tid & 63;
    int e = lane >> 4;       // edge group 0..3
    int f = lane & 15;       // feature
    int node = blockIdx.x * 4 + wave;
    int beg = rowptr[node], end = rowptr[node + 1];
    float dd = dinv[node];

    float acc = 0.0f;
    int j = beg + e;
    for (; j + 4 < end; j += 8) {
        int sA = esrc[j];     float wA = dinv[sA] * dd;
        int sB = esrc[j + 4]; float wB = dinv[sB] * dd;
        float vA = x[sA * N_FEAT + f];
        float vB = x[sB * N_FEAT + f];
        acc += vA * wA + vB * wB;
    }
    if (j < end) {
        int s = esrc[j];
        acc += x[s * N_FEAT + f] * (dinv[s] * dd);
    }
    acc += __shfl_xor(acc, 16, 64);
    acc += __shfl_xor(acc, 32, 64);
    if (e == 0)
        agg16[node * N_FEAT + f] = acc + x[node * N_FEAT + f] * dd * dd;
}

// ---------------- mm1: h1 = bf16(relu(agg16 @ W1 + b1)) ----------------

#define MM1_NODES 16
__global__ __launch_bounds__(256) void k_mm1b(const float* __restrict__ a,
                                              const float* __restrict__ W1,
                                              const float* __restrict__ b1,
                                              __hip_bfloat16* __restrict__ out) {
    __shared__ float sw[N_FEAT][HIDDEN];
    __shared__ float sx[MM1_NODES][N_FEAT + 1];
    int tid = threadIdx.x;
    int n0 = blockIdx.x * MM1_NODES;

    for (int i = tid; i < N_FEAT * HIDDEN; i += 256)
        sw[i >> 7][i & 127] = W1[i];
    if (tid < MM1_NODES * N_FEAT) {
        int n = tid >> 4, k = tid & 15;
        sx[n][k] = a[(n0 + n) * N_FEAT + k];
    }
    __syncthreads();

    int f = tid & 127, half = tid >> 7;
    float bias = b1[f];
    float acc[8] = {0,0,0,0,0,0,0,0};
    #pragma unroll
    for (int k = 0; k < N_FEAT; ++k) {
        float w = sw[k][f];
        #pragma unroll
        for (int i = 0; i < 8; ++i)
            acc[i] += sx[half * 8 + i][k] * w;
    }
    #pragma unroll
    for (int i = 0; i < 8; ++i)
        out[(n0 + half * 8 + i) * HIDDEN + f] =
            __float2bfloat16(fmaxf(acc[i] + bias, 0.0f));
}

// ---------------- layer-2 aggregation, bf16 gather ----------------
// 32 lanes per node, 4 bf16 feats/lane (8B); unroll x4.

__device__ __forceinline__ float bf_lo(unsigned u) {
    union { unsigned i; float f; } c; c.i = u << 16; return c.f;
}
__device__ __forceinline__ float bf_hi(unsigned u) {
    union { unsigned i; float f; } c; c.i = u & 0xffff0000u; return c.f;
}

__global__ __launch_bounds__(256) void k_agg2(const int* __restrict__ rowptr,
                                              const int* __restrict__ esrc,
                                              const float* __restrict__ dinv,
                                              const ushort_t* __restrict__ h1,
                                              float* __restrict__ agg2) {
    int tid = threadIdx.x;
    int sub = tid >> 5;      // 0..7 node within block
    int l32 = tid & 31;      // 8-byte lane within node row
    int node = blockIdx.x * 8 + sub;
    const uint2* h = (const uint2*)h1;   // row = 32 x uint2 (4 bf16 each)
    int beg = rowptr[node], end = rowptr[node + 1];
    float dd = dinv[node];
    uint2 sv = h[node * 32 + l32];
    float dd2 = dd * dd;
    float a0 = bf_lo(sv.x) * dd2, a1 = bf_hi(sv.x) * dd2;
    float a2 = bf_lo(sv.y) * dd2, a3 = bf_hi(sv.y) * dd2;

    int j = beg;
    for (; j + 4 <= end; j += 4) {
        int s0 = esrc[j], s1 = esrc[j + 1], s2 = esrc[j + 2], s3 = esrc[j + 3];
        float w0 = dinv[s0] * dd, w1 = dinv[s1] * dd,
              w2 = dinv[s2] * dd, w3 = dinv[s3] * dd;
        uint2 v0 = h[s0 * 32 + l32];
        uint2 v1 = h[s1 * 32 + l32];
        uint2 v2 = h[s2 * 32 + l32];
        uint2 v3 = h[s3 * 32 + l32];
        a0 += bf_lo(v0.x) * w0 + bf_lo(v1.x) * w1 + bf_lo(v2.x) * w2 + bf_lo(v3.x) * w3;
        a1 += bf_hi(v0.x) * w0 + bf_hi(v1.x) * w1 + bf_hi(v2.x) * w2 + bf_hi(v3.x) * w3;
        a2 += bf_lo(v0.y) * w0 + bf_lo(v1.y) * w1 + bf_lo(v2.y) * w2 + bf_lo(v3.y) * w3;
        a3 += bf_hi(v0.y) * w0 + bf_hi(v1.y) * w1 + bf_hi(v2.y) * w2 + bf_hi(v3.y) * w3;
    }
    for (; j < end; ++j) {
        int s = esrc[j];
        float w = dinv[s] * dd;
        uint2 v = h[s * 32 + l32];
        a0 += bf_lo(v.x) * w; a1 += bf_hi(v.x) * w;
        a2 += bf_lo(v.y) * w; a3 += bf_hi(v.y) * w;
    }
    float4 r = {a0, a1, a2, a3};
    ((float4*)agg2)[node * 32 + l32] = r;
}

// ---------------- mm2 fused head: snode[n] = dot(relu(agg2[n]@W2 + b2), Wl) ----------------

__global__ __launch_bounds__(256) void k_mm2s(const float* __restrict__ h,
                                              const float* __restrict__ W2,
                                              const float* __restrict__ b2,
                                              const float* __restrict__ Wl,
                                              float* __restrict__ snode) {
    __shared__ float sh[HIDDEN][72];   // transposed h tile [k][node]
    __shared__ float sw[32][HIDDEN];   // W2 k-tile
    int tid = threadIdx.x;
    int n0 = blockIdx.x * 64;

    {
        const float4* hv = (const float4*)h;
        #pragma unroll
        for (int j = 0; j < 8; ++j) {
            int q = tid + 256 * j;
            int n = q >> 5;
            int kq = q & 31;
            int gn = n0 + n;
            float4 v = {0.f, 0.f, 0.f, 0.f};
            if (gn < N_NODES) v = hv[gn * 32 + kq];
            int k = kq * 4;
            sh[k][n] = v.x; sh[k + 1][n] = v.y; sh[k + 2][n] = v.z; sh[k + 3][n] = v.w;
        }
    }

    int tcol = tid & 31;
    int trow = tid >> 5;
    float acc[8][4] = {};

    for (int kt = 0; kt < 4; ++kt) {
        __syncthreads();
        {
            const float4* wv = (const float4*)(W2 + kt * 32 * HIDDEN);
            float4* swv = (float4*)(&sw[0][0]);
            #pragma unroll
            for (int j = 0; j < 4; ++j)
                swv[tid + 256 * j] = wv[tid + 256 * j];
        }
        __syncthreads();
        #pragma unroll
        for (int k = 0; k < 32; ++k) {
            int kk = kt * 32 + k;
            float4 wf = *(const float4*)(&sw[k][tcol * 4]);
            float4 a0 = *(const float4*)(&sh[kk][trow * 8]);
            float4 a1 = *(const float4*)(&sh[kk][trow * 8 + 4]);
            float av[8] = {a0.x, a0.y, a0.z, a0.w, a1.x, a1.y, a1.z, a1.w};
            #pragma unroll
            for (int i = 0; i < 8; ++i) {
                acc[i][0] += av[i] * wf.x;
                acc[i][1] += av[i] * wf.y;
                acc[i][2] += av[i] * wf.z;
                acc[i][3] += av[i] * wf.w;
            }
        }
    }

    float4 bv = *(const float4*)(&b2[tcol * 4]);
    float4 wlv = *(const float4*)(&Wl[tcol * 4]);
    float bb[4] = {bv.x, bv.y, bv.z, bv.w};
    float wl[4] = {wlv.x, wlv.y, wlv.z, wlv.w};
    #pragma unroll
    for (int i = 0; i < 8; ++i) {
        float part = 0.0f;
        #pragma unroll
        for (int c = 0; c < 4; ++c)
            part += fmaxf(acc[i][c] + bb[c], 0.0f) * wl[c];
        #pragma unroll
        for (int off = 16; off; off >>= 1)
            part += __shfl_down(part, off, 32);
        int gn = n0 + trow * 8 + i;
        if (tcol == 0 && gn < N_NODES) snode[gn] = part;
    }
}

// ---------------- pooling: out[g] = mean(snode over graph g) + bl ----------------

__global__ __launch_bounds__(256) void k_pool(const float* __restrict__ snode,
                                              const int* __restrict__ batch,
                                              const float* __restrict__ bl,
                                              float* __restrict__ out) {
    int g = blockIdx.x;
    int tid = threadIdx.x;
    __shared__ float sred[4];

    int lo = 0, hi = N_NODES;
    while (lo < hi) { int mid = (lo + hi) >> 1; if (batch[mid] < g) lo = mid + 1; else hi = mid; }
    int start = lo;
    hi = N_NODES;
    while (lo < hi) { int mid = (lo + hi) >> 1; if (batch[mid] < g + 1) lo = mid + 1; else hi = mid; }
    int end = lo;

    float acc = 0.0f;
    for (int n = start + tid; n < end; n += 256) acc += snode[n];

    #pragma unroll
    for (int off = 32; off; off >>= 1) acc += __shfl_down(acc, off, 64);
    int wave = tid >> 6, lane = tid & 63;
    if (lane == 0) sred[wave] = acc;
    __syncthreads();
    if (tid == 0) {
        float s = sred[0] + sred[1] + sred[2] + sred[3];
        float cnt = (float)(end - start);
        out[g] = s / fmaxf(cnt, 1.0f) + bl[0];
    }
}

// ---------------- launch ----------------

extern "C" void kernel_launch(void* const* d_in, const int* in_sizes, int n_in,
                              void* d_out, int out_size, void* d_ws, size_t ws_size,
                              hipStream_t stream) {
    const float* x    = (const float*)d_in[0];
    const int*   src  = (const int*)d_in[1];
    const int*   dst  = src + N_EDGES;
    const int*   batch= (const int*)d_in[2];
    const float* W1   = (const float*)d_in[3];
    const float* b1   = (const float*)d_in[4];
    const float* W2   = (const float*)d_in[5];
    const float* b2   = (const float*)d_in[6];
    const float* Wl   = (const float*)d_in[7];
    const float* bl   = (const float*)d_in[8];
    float* out = (float*)d_out;

    const size_t NH = (size_t)N_NODES * HIDDEN;

    __hip_bfloat16* h1 = (__hip_bfloat16*)d_ws;       // NH bf16 (25.6 MB)
    float* agg2  = (float*)((char*)d_ws + NH * 2);    // NH fp32
    float* agg16 = agg2;                               // aliases (dead before agg2)
    float* dinv  = agg2 + NH;                          // N_NODES
    float* snode = dinv + N_NODES;                     // N_NODES
    int*   cnt    = (int*)(snode + N_NODES);           // N_NODES
    int*   rowptr = cnt + N_NODES;                     // N_NODES+1
    int*   rank   = rowptr + N_NODES + 1;              // N_EDGES
    int*   bsum   = rank + N_EDGES;                    // NB_SCAN
    int*   boff   = bsum + NB_SCAN;                    // NB_SCAN
    int*   esrc   = boff + NB_SCAN;                    // N_EDGES

    // CSR build
    hipMemsetAsync(cnt, 0, N_NODES * sizeof(int), stream);
    k_deg<<<(N_EDGES + 255) / 256, 256, 0, stream>>>(dst, cnt, rank);
    k_bsum<<<NB_SCAN, 256, 0, stream>>>(cnt, bsum);
    k_scanb<<<1, 512, 0, stream>>>(bsum, boff);
    k_scanf<<<NB_SCAN, 256, 0, stream>>>(cnt, boff, rowptr, dinv);
    k_bucket<<<(N_EDGES + 255) / 256, 256, 0, stream>>>(src, dst, rank, rowptr, esrc);

    // layer 1: aggregate in 16-dim, then matmul -> bf16 h1
    k_agg1<<<N_NODES / 4, 256, 0, stream>>>(rowptr, esrc, dinv, x, agg16);
    k_mm1b<<<N_NODES / MM1_NODES, 256, 0, stream>>>(agg16, W1, b1, h1);

    // layer 2: bf16 gather aggregate, fused mm2 + head dot
    k_agg2<<<N_NODES / 8, 256, 0, stream>>>(rowptr, esrc, dinv, (const ushort_t*)h1, agg2);
    k_mm2s<<<(N_NODES + 63) / 64, 256, 0, stream>>>(agg2, W2, b2, Wl, snode);

    // pool + bias
    k_pool<<<N_GRAPHS, 256, 0, stream>>>(snode, batch, bl, out);
}